// Round 1
// baseline (2907.123 us; speedup 1.0000x reference)
//
#include <hip/hip_runtime.h>

#define NB 16
#define NPT 1024
#define NP 512
#define NS 32
#define DF 64
#define RAD2 0.04f
#define EPSQ 1e-5f
#define CNT 786432.0f   // 48*512*32

// --- np-matching (contraction-proof) arithmetic -------------------------
__device__ __forceinline__ float rmul(float a, float b){ return __fmul_rn(a,b); }
__device__ __forceinline__ float radd(float a, float b){ return __fadd_rn(a,b); }
// sum of 3 squares in np order: ((a*a + b*b) + c*c), no fma
__device__ __forceinline__ float sq3(float a, float b, float c){
  return radd(radd(rmul(a,a), rmul(b,b)), rmul(c,c));
}

__device__ __forceinline__ float wave_sum64(float v){
  #pragma unroll
  for(int m=1;m<64;m<<=1) v += __shfl_xor(v, m, 64);
  return v;
}

// ======================= FPS =======================
// 1 block per batch, 256 threads, 4 points/thread. Writes new_xyz in
// (B,3,NPOINT) layout directly into d_out[0:24576].
__global__ __launch_bounds__(256) void fps_kernel(const float* __restrict__ xyz,
                                                  float* __restrict__ out0){
  const int b = blockIdx.x;
  const int t = threadIdx.x;
  const int lane = t & 63;
  const int wv = t >> 6;
  const float* xb = xyz + b*3*NPT;
  float px[4], py[4], pz[4], dist[4];
  #pragma unroll
  for(int i=0;i<4;i++){
    int n = i*256 + t;
    px[i] = xb[n]; py[i] = xb[NPT+n]; pz[i] = xb[2*NPT+n];
  }
  __shared__ float lsv[4]; __shared__ int lsi[4];
  __shared__ float sel[3]; __shared__ int sfar;
  __shared__ float cred[3][4];
  // centroid = mean over n
  float sx=0.f, sy=0.f, sz=0.f;
  #pragma unroll
  for(int i=0;i<4;i++){ sx+=px[i]; sy+=py[i]; sz+=pz[i]; }
  sx = wave_sum64(sx); sy = wave_sum64(sy); sz = wave_sum64(sz);
  if(lane==0){ cred[0][wv]=sx; cred[1][wv]=sy; cred[2][wv]=sz; }
  __syncthreads();
  float cx = (cred[0][0]+cred[0][1]+cred[0][2]+cred[0][3]) / 1024.0f;
  float cy = (cred[1][0]+cred[1][1]+cred[1][2]+cred[1][3]) / 1024.0f;
  float cz = (cred[2][0]+cred[2][1]+cred[2][2]+cred[2][3]) / 1024.0f;
  // initial distance + argmax (first-index tie break)
  float bv = -1.0f; int bi = 0;
  #pragma unroll
  for(int i=0;i<4;i++){
    float dx = px[i]-cx, dy = py[i]-cy, dz = pz[i]-cz;
    float d = fminf(1e10f, sq3(dx,dy,dz));
    dist[i] = d;
    int n = i*256+t;
    if(d > bv){ bv = d; bi = n; }
  }
  #pragma unroll
  for(int m=1;m<64;m<<=1){
    float ov = __shfl_xor(bv, m, 64); int oi = __shfl_xor(bi, m, 64);
    if(ov > bv || (ov == bv && oi < bi)){ bv = ov; bi = oi; }
  }
  if(lane==0){ lsv[wv]=bv; lsi[wv]=bi; }
  __syncthreads();
  if(t==0){
    float v = lsv[0]; int ix = lsi[0];
    for(int w=1;w<4;w++){ if(lsv[w] > v || (lsv[w]==v && lsi[w]<ix)){ v=lsv[w]; ix=lsi[w]; } }
    sfar = ix;
  }
  __syncthreads();
  for(int it=0; it<NP; ++it){
    int far = sfar;
    if(t == (far & 255)){
      int slidx = far >> 8;
      float ox = px[slidx], oy = py[slidx], oz = pz[slidx];
      sel[0]=ox; sel[1]=oy; sel[2]=oz;
      out0[(b*3+0)*NP + it] = ox;
      out0[(b*3+1)*NP + it] = oy;
      out0[(b*3+2)*NP + it] = oz;
    }
    __syncthreads();
    float qx=sel[0], qy=sel[1], qz=sel[2];
    bv = -1.0f; bi = 0;
    #pragma unroll
    for(int i=0;i<4;i++){
      float dx=px[i]-qx, dy=py[i]-qy, dz=pz[i]-qz;
      float nd = sq3(dx,dy,dz);
      float d = fminf(dist[i], nd);
      dist[i] = d;
      if(d > bv){ bv = d; bi = i*256+t; }
    }
    #pragma unroll
    for(int m=1;m<64;m<<=1){
      float ov = __shfl_xor(bv, m, 64); int oi = __shfl_xor(bi, m, 64);
      if(ov > bv || (ov == bv && oi < bi)){ bv=ov; bi=oi; }
    }
    if(lane==0){ lsv[wv]=bv; lsi[wv]=bi; }
    __syncthreads();
    if(t==0){
      float v = lsv[0]; int ix = lsi[0];
      for(int w=1;w<4;w++){ if(lsv[w] > v || (lsv[w]==v && lsi[w]<ix)){ v=lsv[w]; ix=lsi[w]; } }
      sfar = ix;
    }
    __syncthreads();
  }
}

// ======================= Ball query =======================
// 1 wave per (b,s): ordered first-32-within-radius via ballot prefix.
__global__ __launch_bounds__(256) void ball_kernel(const float* __restrict__ xyz,
                                                   const float* __restrict__ out0,
                                                   int* __restrict__ idxb){
  const int gw = (blockIdx.x * 256 + threadIdx.x) >> 6;
  const int lane = threadIdx.x & 63;
  const int b = gw >> 9;
  const int s = gw & 511;
  const float s0 = out0[(b*3+0)*NP + s];
  const float s1 = out0[(b*3+1)*NP + s];
  const float s2 = out0[(b*3+2)*NP + s];
  const float ss = sq3(s0,s1,s2);
  const float* xb = xyz + b*3*NPT;
  int base = 0; int firstn = -1;
  int* row = idxb + (b*NP + s)*NS;
  for(int chk=0; chk<16 && base<NS; ++chk){
    const int n = chk*64 + lane;
    float d0 = xb[n], d1 = xb[NPT+n], d2 = xb[2*NPT+n];
    float dd = sq3(d0,d1,d2);
    float p  = radd(radd(rmul(s0,d0), rmul(s1,d1)), rmul(s2,d2));
    // sqr = ((-2*p) + ss) + dd   -- exact np formula/order
    float sqr = radd(radd(rmul(-2.0f,p), ss), dd);
    bool inc = !(sqr > RAD2);
    unsigned long long mask = __ballot(inc);
    if(inc){
      int slot = base + __popcll(mask & ((1ull<<lane)-1ull));
      if(slot < NS) row[slot] = n;
    }
    if(firstn < 0 && mask != 0ull) firstn = chk*64 + (__ffsll((unsigned long long)mask) - 1);
    base += __popcll(mask);
  }
  for(int slot = base + lane; slot < NS; slot += 64) row[slot] = firstn;
}

// ======================= Fused MLP chain passes =======================
// Block = 384 threads: t = (c3*4 + s_local)*32 + k, tile = 4 s-values.
// DEPTH=1: GEMM0 -> stats1. DEPTH=2: ...->qrelu1->GEMM1->stats2.
// DEPTH=3: ...->qrelu2->GEMM2->stats3 + argmax over k -> raw x3 into out1.
template<int DEPTH>
__global__ __launch_bounds__(384) void pass_kernel(
  const float* __restrict__ xyz, const float* __restrict__ pts,
  const float* __restrict__ W0, const float* __restrict__ W1, const float* __restrict__ W2,
  const float* __restrict__ out0, const int* __restrict__ idxb,
  const float* __restrict__ inv1, const float* __restrict__ inv2,
  float* __restrict__ part, float* __restrict__ out1)
{
  const int t = threadIdx.x;
  const int c3 = t >> 7;       // component 0..2
  const int r  = t & 127;      // sample within tile (s_local*32 + k)
  const int sl = r >> 5;
  const int k  = r & 31;
  const int lane = t & 63;
  const int wv = t >> 6;       // wave 0..5 (c3 = wv/2)
  const int bi = blockIdx.x;
  const int b = bi >> 7;
  const int s = ((bi & 127) << 2) + sl;

  __shared__ float sq[3][128][17];
  __shared__ float wstat[6][128];
  for(int i=t; i<6*128; i+=384) (&wstat[0][0])[i] = 0.f;
  __syncthreads();

  const int n = idxb[(b*NP + s)*NS + k];
  const int b3 = b*3 + c3;
  const float gx = xyz[b3*NPT + n];
  const float cx = out0[b3*NP + s];
  float x0[66];
  x0[0] = gx - cx;   // g_norm
  x0[1] = gx;        // g_xyz
  {
    const float* pr = pts + ((size_t)b3*DF)*NPT + n;
    #pragma unroll
    for(int c=0;c<DF;c++) x0[2+c] = pr[(size_t)c*NPT];
  }

  // ---- layer 0 ----
  float y1[64];
  #pragma unroll
  for(int ch=0; ch<4; ++ch){
    float acc[16];
    #pragma unroll
    for(int oo=0;oo<16;oo++){
      const int o = ch*16+oo;
      float a = 0.f;
      #pragma unroll
      for(int c=0;c<66;c++) a = fmaf(W0[o*66+c], x0[c], a);
      acc[oo] = a;
    }
    if constexpr(DEPTH == 1){
      #pragma unroll
      for(int oo=0;oo<16;oo++){
        float v = wave_sum64(acc[oo]*acc[oo]);
        if(lane==0) wstat[wv][ch*16+oo] += v;
      }
    } else {
      #pragma unroll
      for(int oo=0;oo<16;oo++){
        float xp = acc[oo] * inv1[ch*16+oo];
        acc[oo] = xp;
        sq[c3][r][oo] = xp*xp;
      }
      __syncthreads();
      #pragma unroll
      for(int oo=0;oo<16;oo++){
        float m2 = (sq[0][r][oo] + sq[1][r][oo]) + sq[2][r][oo];
        float mod = sqrtf(m2);
        float cf = (mod >= 1.f) ? 1.f : mod;
        y1[ch*16+oo] = cf * acc[oo];
      }
      __syncthreads();
    }
  }
  if constexpr(DEPTH == 1){
    __syncthreads();
    if(t < 64){
      float sv = 0.f;
      #pragma unroll
      for(int w=0;w<6;w++) sv += wstat[w][t];
      part[bi*64 + t] = sv;
    }
    return;
  }

  // ---- layer 1 ----
  float y2[64];
  #pragma unroll
  for(int ch=0; ch<4; ++ch){
    float acc[16];
    #pragma unroll
    for(int oo=0;oo<16;oo++){
      const int o = ch*16+oo;
      float a = 0.f;
      #pragma unroll
      for(int c=0;c<64;c++) a = fmaf(W1[o*64+c], y1[c], a);
      acc[oo] = a;
    }
    if constexpr(DEPTH == 2){
      #pragma unroll
      for(int oo=0;oo<16;oo++){
        float v = wave_sum64(acc[oo]*acc[oo]);
        if(lane==0) wstat[wv][ch*16+oo] += v;
      }
    } else {
      #pragma unroll
      for(int oo=0;oo<16;oo++){
        float xp = acc[oo] * inv2[ch*16+oo];
        acc[oo] = xp;
        sq[c3][r][oo] = xp*xp;
      }
      __syncthreads();
      #pragma unroll
      for(int oo=0;oo<16;oo++){
        float m2 = (sq[0][r][oo] + sq[1][r][oo]) + sq[2][r][oo];
        float mod = sqrtf(m2);
        float cf = (mod >= 1.f) ? 1.f : mod;
        y2[ch*16+oo] = cf * acc[oo];
      }
      __syncthreads();
    }
  }
  if constexpr(DEPTH == 2){
    __syncthreads();
    if(t < 64){
      float sv = 0.f;
      #pragma unroll
      for(int w=0;w<6;w++) sv += wstat[w][t];
      part[bi*64 + t] = sv;
    }
    return;
  }

  // ---- layer 2 + argmax over k + stats3 ----
  #pragma unroll
  for(int ch=0; ch<8; ++ch){
    float acc[16];
    #pragma unroll
    for(int oo=0;oo<16;oo++){
      const int o = ch*16+oo;
      float a = 0.f;
      #pragma unroll
      for(int c=0;c<64;c++) a = fmaf(W2[o*64+c], y2[c], a);
      acc[oo] = a;
      sq[c3][r][oo] = a*a;   // raw x3^2
    }
    __syncthreads();
    #pragma unroll
    for(int oo=0;oo<16;oo++){
      const int o = ch*16+oo;
      float m2 = (sq[0][r][oo] + sq[1][r][oo]) + sq[2][r][oo];
      // argmax over k within the 32-lane group (tie -> lowest k)
      float v = m2; int ki = k;
      #pragma unroll
      for(int m=1;m<32;m<<=1){
        float ov = __shfl_xor(v, m, 32);
        int oki = __shfl_xor(ki, m, 32);
        if(ov > v || (ov == v && oki < ki)){ v = ov; ki = oki; }
      }
      if(k == ki){
        out1[((size_t)b3*128 + o)*NP + s] = acc[oo];  // raw x3 of winner
      }
      if(c3 == 0){  // wave-uniform branch
        float sv = wave_sum64(m2);
        if(lane==0) wstat[wv][o] += sv;
      }
    }
    __syncthreads();
  }
  if(t < 128){
    part[bi*128 + t] = wstat[0][t] + wstat[1][t];
  }
}

// ======================= stats finalize =======================
__global__ __launch_bounds__(256) void fin_kernel(const float* __restrict__ part, int nblk, int nch,
                                                  float* __restrict__ inv){
  const int o = blockIdx.x;
  const int t = threadIdx.x;
  float sum = 0.f;
  for(int i=t; i<nblk; i+=256) sum += part[(size_t)i*nch + o];
  sum = wave_sum64(sum);
  __shared__ float red[4];
  if((t&63)==0) red[t>>6] = sum;
  __syncthreads();
  if(t==0){
    float tot = (red[0]+red[1])+(red[2]+red[3]);
    inv[o] = 1.0f / sqrtf(tot/CNT + EPSQ);
  }
}

// ======================= final qbn+qrelu on picked values =======================
__global__ __launch_bounds__(256) void scale_kernel(float* __restrict__ out,
                                                    const float* __restrict__ inv3){
  const int tid = blockIdx.x*256 + threadIdx.x;
  if(tid >= NB*128*NP) return;
  const int s = tid & 511;
  const int o = (tid >> 9) & 127;
  const int b = tid >> 16;
  float* base = out + NB*3*NP;
  const size_t str = (size_t)128*NP;
  size_t i0 = ((size_t)(b*3)*128 + o)*NP + s;
  float iv = inv3[o];
  float a0 = base[i0] * iv;
  float a1 = base[i0+str] * iv;
  float a2 = base[i0+2*str] * iv;
  float m2 = (a0*a0 + a1*a1) + a2*a2;
  float mod = sqrtf(m2);
  float cf = (mod >= 1.f) ? 1.f : mod;
  base[i0] = cf*a0; base[i0+str] = cf*a1; base[i0+2*str] = cf*a2;
}

// ======================= host =======================
extern "C" void kernel_launch(void* const* d_in, const int* in_sizes, int n_in,
                              void* d_out, int out_size, void* d_ws, size_t ws_size,
                              hipStream_t stream){
  const float* xyz = (const float*)d_in[0];
  const float* pts = (const float*)d_in[1];
  const float* W0  = (const float*)d_in[2];
  const float* W1  = (const float*)d_in[3];
  const float* W2  = (const float*)d_in[4];
  float* out = (float*)d_out;
  char* ws = (char*)d_ws;
  int*   idxb  = (int*)ws;                                  // 16*512*32 ints = 1 MB
  float* part1 = (float*)(ws + (size_t)NB*NP*NS*4);         // 2048*64
  float* part2 = part1 + 2048*64;
  float* part3 = part2 + 2048*64;                           // 2048*128
  float* inv1  = part3 + 2048*128;
  float* inv2  = inv1 + 64;
  float* inv3  = inv2 + 64;
  float* out1  = out + NB*3*NP;

  fps_kernel<<<NB, 256, 0, stream>>>(xyz, out);
  ball_kernel<<<2048, 256, 0, stream>>>(xyz, out, idxb);
  pass_kernel<1><<<2048, 384, 0, stream>>>(xyz, pts, W0, W1, W2, out, idxb, nullptr, nullptr, part1, nullptr);
  fin_kernel<<<64, 256, 0, stream>>>(part1, 2048, 64, inv1);
  pass_kernel<2><<<2048, 384, 0, stream>>>(xyz, pts, W0, W1, W2, out, idxb, inv1, nullptr, part2, nullptr);
  fin_kernel<<<64, 256, 0, stream>>>(part2, 2048, 64, inv2);
  pass_kernel<3><<<2048, 384, 0, stream>>>(xyz, pts, W0, W1, W2, out, idxb, inv1, inv2, part3, out1);
  fin_kernel<<<128, 256, 0, stream>>>(part3, 2048, 128, inv3);
  scale_kernel<<<(NB*128*NP + 255)/256, 256, 0, stream>>>(out, inv3);
}